// Round 1
// baseline (2273.358 us; speedup 1.0000x reference)
//
#include <hip/hip_runtime.h>
#include <hip/hip_bf16.h>

#define F_IN 512
#define HID 32
#define HEADS 8
#define C1 (HEADS*HID)   // 256
#define CLS 64
#define NEG 0.2f
#define EPS 1e-16f

__device__ __forceinline__ void atomicMaxF(float* addr, float val) {
  // works for all-float ordering given init bits 0xFFFFFFFF (int -1 / uint max)
  if (val >= 0.f) atomicMax((int*)addr, __float_as_int(val));
  else            atomicMin((unsigned int*)addr, __float_as_uint(val));
}

__device__ __forceinline__ float leaky(float v) { return v > 0.f ? v : NEG * v; }

// ---------------- GEMM: C[M,NCOLS] = A[M,K] @ B[K,NCOLS], fp32 ----------------
template<int NCOLS, int ROWS, int KT>
__global__ __launch_bounds__(256) void gemm_rt(const float* __restrict__ A,
                                               const float* __restrict__ B,
                                               float* __restrict__ C, int M, int K) {
  __shared__ float At[ROWS][KT];
  constexpr int RPT = ROWS * NCOLS / 256;  // rows per thread
  const int t   = threadIdx.x;
  const int r0  = blockIdx.x * ROWS;
  const int col = t % NCOLS;
  const int rg  = t / NCOLS;
  float acc[RPT];
#pragma unroll
  for (int i = 0; i < RPT; i++) acc[i] = 0.f;

  for (int k0 = 0; k0 < K; k0 += KT) {
    for (int idx = t; idx < ROWS * KT; idx += 256) {
      int rr = idx / KT, kk = idx % KT;
      int r = r0 + rr;
      At[rr][kk] = (r < M) ? A[(size_t)r * K + (k0 + kk)] : 0.f;
    }
    __syncthreads();
    for (int k = 0; k < KT; k += 4) {
      float b0 = B[(size_t)(k0 + k) * NCOLS + col];
      float b1 = B[(size_t)(k0 + k + 1) * NCOLS + col];
      float b2 = B[(size_t)(k0 + k + 2) * NCOLS + col];
      float b3 = B[(size_t)(k0 + k + 3) * NCOLS + col];
#pragma unroll
      for (int i = 0; i < RPT; i++) {
        const float4 a4 = *(const float4*)&At[rg * RPT + i][k];
        acc[i] += a4.x * b0 + a4.y * b1 + a4.z * b2 + a4.w * b3;
      }
    }
    __syncthreads();
  }
#pragma unroll
  for (int i = 0; i < RPT; i++) {
    int r = r0 + rg * RPT + i;
    if (r < M) C[(size_t)r * NCOLS + col] = acc[i];
  }
}

// ---------------- attention score dots ----------------
// layer1: block 256 = one node; t -> (h = t/32, c = t%32)
__global__ __launch_bounds__(256) void att_scores1(const float* __restrict__ h1,
    const float* __restrict__ asw, const float* __restrict__ adw,
    float* __restrict__ a_src, float* __restrict__ a_dst) {
  int n = blockIdx.x, t = threadIdx.x;
  float v  = h1[(size_t)n * C1 + t];
  float ps = v * asw[t];
  float pd = v * adw[t];
#pragma unroll
  for (int o = 16; o >= 1; o >>= 1) {
    ps += __shfl_xor(ps, o);
    pd += __shfl_xor(pd, o);
  }
  if ((t & 31) == 0) {
    a_src[n * HEADS + (t >> 5)] = ps;
    a_dst[n * HEADS + (t >> 5)] = pd;
  }
}

// layer2: block 64 = one node (1 head, 64 ch)
__global__ __launch_bounds__(64) void att_scores2(const float* __restrict__ h2,
    const float* __restrict__ asw, const float* __restrict__ adw,
    float* __restrict__ a_src, float* __restrict__ a_dst) {
  int n = blockIdx.x, c = threadIdx.x;
  float v  = h2[(size_t)n * CLS + c];
  float ps = v * asw[c];
  float pd = v * adw[c];
#pragma unroll
  for (int o = 32; o >= 1; o >>= 1) {
    ps += __shfl_xor(ps, o);
    pd += __shfl_xor(pd, o);
  }
  if (c == 0) { a_src[n] = ps; a_dst[n] = pd; }
}

// ---------------- edge passes, layer 1 (8 heads) ----------------
__global__ __launch_bounds__(256) void edge_max1(const int* __restrict__ ei,
    const float* __restrict__ as1, const float* __restrict__ ad1,
    float* __restrict__ m1, int E, int EL) {
  int e = blockIdx.x * 256 + threadIdx.x;
  if (e >= EL) return;
  int s, d;
  if (e < E) { s = ei[e]; d = ei[E + e]; } else { s = d = e - E; }
  const float4* pa = (const float4*)(as1 + (size_t)s * HEADS);
  const float4* pb = (const float4*)(ad1 + (size_t)d * HEADS);
  float4 a0 = pa[0], a1 = pa[1], b0 = pb[0], b1 = pb[1];
  float v[8] = {a0.x + b0.x, a0.y + b0.y, a0.z + b0.z, a0.w + b0.w,
                a1.x + b1.x, a1.y + b1.y, a1.z + b1.z, a1.w + b1.w};
#pragma unroll
  for (int h = 0; h < 8; h++) atomicMaxF(&m1[(size_t)d * HEADS + h], leaky(v[h]));
}

__global__ __launch_bounds__(256) void edge_sum1(const int* __restrict__ ei,
    const float* __restrict__ as1, const float* __restrict__ ad1,
    const float* __restrict__ m1, float* __restrict__ s1, int E, int EL) {
  int e = blockIdx.x * 256 + threadIdx.x;
  if (e >= EL) return;
  int s, d;
  if (e < E) { s = ei[e]; d = ei[E + e]; } else { s = d = e - E; }
  const float4* pa = (const float4*)(as1 + (size_t)s * HEADS);
  const float4* pb = (const float4*)(ad1 + (size_t)d * HEADS);
  const float4* pm = (const float4*)(m1 + (size_t)d * HEADS);
  float4 a0 = pa[0], a1 = pa[1], b0 = pb[0], b1 = pb[1];
  float4 m0 = pm[0], m1_ = pm[1];
  float v[8] = {a0.x + b0.x, a0.y + b0.y, a0.z + b0.z, a0.w + b0.w,
                a1.x + b1.x, a1.y + b1.y, a1.z + b1.z, a1.w + b1.w};
  float mm[8] = {m0.x, m0.y, m0.z, m0.w, m1_.x, m1_.y, m1_.z, m1_.w};
#pragma unroll
  for (int h = 0; h < 8; h++)
    unsafeAtomicAdd(&s1[(size_t)d * HEADS + h], __expf(leaky(v[h]) - mm[h]));
}

// block 256 = one edge; t -> (h = t/32, c = t%32); out1[d,t] += h1[s,t]*alpha[h]
__global__ __launch_bounds__(256) void aggr1(const int* __restrict__ ei,
    const float* __restrict__ h1, const float* __restrict__ as1,
    const float* __restrict__ ad1, const float* __restrict__ m1,
    const float* __restrict__ s1, float* __restrict__ out1, int E, int EL) {
  int e = blockIdx.x;
  int t = threadIdx.x;
  int s, d;
  if (e < E) { s = ei[e]; d = ei[E + e]; } else { s = d = e - E; }
  int h = t >> 5;
  float v = leaky(as1[(size_t)s * HEADS + h] + ad1[(size_t)d * HEADS + h]);
  float alpha = __expf(v - m1[(size_t)d * HEADS + h]) / (s1[(size_t)d * HEADS + h] + EPS);
  unsafeAtomicAdd(&out1[(size_t)d * C1 + t], h1[(size_t)s * C1 + t] * alpha);
}

// ---------------- relu + bias (b1 is zeros but keep semantics) ----------------
__global__ __launch_bounds__(256) void relu_bias(float* __restrict__ o,
    const float* __restrict__ b, int total) {
  int i = blockIdx.x * 256 + threadIdx.x;
  if (i < total) {
    float v = o[i] + b[i & (C1 - 1)];
    o[i] = v > 0.f ? v : 0.f;
  }
}

// ---------------- edge passes, layer 2 (1 head) ----------------
__global__ __launch_bounds__(256) void edge_max2(const int* __restrict__ ei,
    const float* __restrict__ as2, const float* __restrict__ ad2,
    float* __restrict__ m2, int E, int EL) {
  int e = blockIdx.x * 256 + threadIdx.x;
  if (e >= EL) return;
  int s, d;
  if (e < E) { s = ei[e]; d = ei[E + e]; } else { s = d = e - E; }
  atomicMaxF(&m2[d], leaky(as2[s] + ad2[d]));
}

__global__ __launch_bounds__(256) void edge_sum2(const int* __restrict__ ei,
    const float* __restrict__ as2, const float* __restrict__ ad2,
    const float* __restrict__ m2, float* __restrict__ s2, int E, int EL) {
  int e = blockIdx.x * 256 + threadIdx.x;
  if (e >= EL) return;
  int s, d;
  if (e < E) { s = ei[e]; d = ei[E + e]; } else { s = d = e - E; }
  unsafeAtomicAdd(&s2[d], __expf(leaky(as2[s] + ad2[d]) - m2[d]));
}

// block 256 = 4 edges x 64 lanes
__global__ __launch_bounds__(256) void aggr2(const int* __restrict__ ei,
    const float* __restrict__ h2, const float* __restrict__ as2,
    const float* __restrict__ ad2, const float* __restrict__ m2,
    const float* __restrict__ s2, float* __restrict__ out, int E, int EL) {
  int e = blockIdx.x * 4 + (threadIdx.x >> 6);
  int c = threadIdx.x & 63;
  if (e >= EL) return;
  int s, d;
  if (e < E) { s = ei[e]; d = ei[E + e]; } else { s = d = e - E; }
  float v = leaky(as2[s] + ad2[d]);
  float alpha = __expf(v - m2[d]) / (s2[d] + EPS);
  unsafeAtomicAdd(&out[(size_t)d * CLS + c], h2[(size_t)s * CLS + c] * alpha);
}

// ---------------- final: out = log_softmax(out + b2), in place; 4 nodes/block ----------------
__global__ __launch_bounds__(256) void final_lsm(float* __restrict__ out,
    const float* __restrict__ b2, int N) {
  int n = blockIdx.x * 4 + (threadIdx.x >> 6);
  int c = threadIdx.x & 63;
  if (n >= N) return;
  float v = out[(size_t)n * CLS + c] + b2[c];
  float mx = v;
#pragma unroll
  for (int o = 32; o >= 1; o >>= 1) mx = fmaxf(mx, __shfl_xor(mx, o));
  float ex = __expf(v - mx);
  float sm = ex;
#pragma unroll
  for (int o = 32; o >= 1; o >>= 1) sm += __shfl_xor(sm, o);
  out[(size_t)n * CLS + c] = v - mx - __logf(sm);
}

extern "C" void kernel_launch(void* const* d_in, const int* in_sizes, int n_in,
                              void* d_out, int out_size, void* d_ws, size_t ws_size,
                              hipStream_t stream) {
  const float* x        = (const float*)d_in[0];
  const int*   ei       = (const int*)d_in[1];
  const float* W1       = (const float*)d_in[2];
  const float* att_src1 = (const float*)d_in[3];
  const float* att_dst1 = (const float*)d_in[4];
  const float* b1       = (const float*)d_in[5];
  const float* W2       = (const float*)d_in[6];
  const float* att_src2 = (const float*)d_in[7];
  const float* att_dst2 = (const float*)d_in[8];
  const float* b2       = (const float*)d_in[9];
  float* out = (float*)d_out;

  const int N  = in_sizes[0] / F_IN;   // 50000
  const int E  = in_sizes[1] / 2;      // 800000
  const int EL = E + N;                // + self loops

  char* ws = (char*)d_ws;
  size_t off = 0;
  auto alloc = [&](size_t bytes) -> void* {
    void* p = ws + off;
    off += (bytes + 255) & ~(size_t)255;
    return p;
  };
  float* h1  = (float*)alloc((size_t)N * C1 * 4);
  float* o1  = (float*)alloc((size_t)N * C1 * 4);
  float* as1 = (float*)alloc((size_t)N * HEADS * 4);
  float* ad1 = (float*)alloc((size_t)N * HEADS * 4);
  float* m1  = (float*)alloc((size_t)N * HEADS * 4);
  float* s1  = (float*)alloc((size_t)N * HEADS * 4);
  float* h2  = (float*)alloc((size_t)N * CLS * 4);
  float* as2 = (float*)alloc((size_t)N * 4);
  float* ad2 = (float*)alloc((size_t)N * 4);
  float* m2  = (float*)alloc((size_t)N * 4);
  float* s2  = (float*)alloc((size_t)N * 4);

  hipMemsetAsync(o1, 0,    (size_t)N * C1 * 4, stream);
  hipMemsetAsync(s1, 0,    (size_t)N * HEADS * 4, stream);
  hipMemsetAsync(m1, 0xFF, (size_t)N * HEADS * 4, stream);  // "-NaN" = bottom for atomicMaxF
  hipMemsetAsync(out, 0,   (size_t)N * CLS * 4, stream);
  hipMemsetAsync(s2, 0,    (size_t)N * 4, stream);
  hipMemsetAsync(m2, 0xFF, (size_t)N * 4, stream);

  // ---- layer 1 ----
  gemm_rt<C1, 32, 64><<<(N + 31) / 32, 256, 0, stream>>>(x, W1, h1, N, F_IN);
  att_scores1<<<N, 256, 0, stream>>>(h1, att_src1, att_dst1, as1, ad1);
  edge_max1<<<(EL + 255) / 256, 256, 0, stream>>>(ei, as1, ad1, m1, E, EL);
  edge_sum1<<<(EL + 255) / 256, 256, 0, stream>>>(ei, as1, ad1, m1, s1, E, EL);
  aggr1<<<EL, 256, 0, stream>>>(ei, h1, as1, ad1, m1, s1, o1, E, EL);
  relu_bias<<<(N * C1 + 255) / 256, 256, 0, stream>>>(o1, b1, N * C1);

  // ---- layer 2 ----
  gemm_rt<CLS, 64, 64><<<(N + 63) / 64, 256, 0, stream>>>(o1, W2, h2, N, C1);
  att_scores2<<<N, 64, 0, stream>>>(h2, att_src2, att_dst2, as2, ad2);
  edge_max2<<<(EL + 255) / 256, 256, 0, stream>>>(ei, as2, ad2, m2, E, EL);
  edge_sum2<<<(EL + 255) / 256, 256, 0, stream>>>(ei, as2, ad2, m2, s2, E, EL);
  aggr2<<<(EL + 3) / 4, 256, 0, stream>>>(ei, h2, as2, ad2, m2, s2, out, E, EL);

  // ---- log_softmax ----
  final_lsm<<<(N + 3) / 4, 256, 0, stream>>>(out, b2, N);
}

// Round 2
// 1016.715 us; speedup vs baseline: 2.2360x; 2.2360x over previous
//
#include <hip/hip_runtime.h>
#include <hip/hip_bf16.h>

#define F_IN 512
#define HID 32
#define HEADS 8
#define C1 (HEADS*HID)   // 256
#define CLS 64
#define NEG 0.2f
#define EPS 1e-16f

__device__ __forceinline__ float leaky(float v) { return v > 0.f ? v : NEG * v; }

// ---------------- GEMM: C[M,NCOLS] = A[M,K] @ B[K,NCOLS], fp32 ----------------
template<int NCOLS, int ROWS, int KT>
__global__ __launch_bounds__(256) void gemm_rt(const float* __restrict__ A,
                                               const float* __restrict__ B,
                                               float* __restrict__ C, int M, int K) {
  __shared__ float At[ROWS][KT];
  constexpr int RPT = ROWS * NCOLS / 256;  // rows per thread
  const int t   = threadIdx.x;
  const int r0  = blockIdx.x * ROWS;
  const int col = t % NCOLS;
  const int rg  = t / NCOLS;
  float acc[RPT];
#pragma unroll
  for (int i = 0; i < RPT; i++) acc[i] = 0.f;

  for (int k0 = 0; k0 < K; k0 += KT) {
    for (int idx = t; idx < ROWS * KT; idx += 256) {
      int rr = idx / KT, kk = idx % KT;
      int r = r0 + rr;
      At[rr][kk] = (r < M) ? A[(size_t)r * K + (k0 + kk)] : 0.f;
    }
    __syncthreads();
    for (int k = 0; k < KT; k += 4) {
      float b0 = B[(size_t)(k0 + k) * NCOLS + col];
      float b1 = B[(size_t)(k0 + k + 1) * NCOLS + col];
      float b2 = B[(size_t)(k0 + k + 2) * NCOLS + col];
      float b3 = B[(size_t)(k0 + k + 3) * NCOLS + col];
#pragma unroll
      for (int i = 0; i < RPT; i++) {
        const float4 a4 = *(const float4*)&At[rg * RPT + i][k];
        acc[i] += a4.x * b0 + a4.y * b1 + a4.z * b2 + a4.w * b3;
      }
    }
    __syncthreads();
  }
#pragma unroll
  for (int i = 0; i < RPT; i++) {
    int r = r0 + rg * RPT + i;
    if (r < M) C[(size_t)r * NCOLS + col] = acc[i];
  }
}

// ---------------- attention score dots ----------------
__global__ __launch_bounds__(256) void att_scores1(const float* __restrict__ h1,
    const float* __restrict__ asw, const float* __restrict__ adw,
    float* __restrict__ a_src, float* __restrict__ a_dst) {
  int n = blockIdx.x, t = threadIdx.x;
  float v  = h1[(size_t)n * C1 + t];
  float ps = v * asw[t];
  float pd = v * adw[t];
#pragma unroll
  for (int o = 16; o >= 1; o >>= 1) {
    ps += __shfl_xor(ps, o);
    pd += __shfl_xor(pd, o);
  }
  if ((t & 31) == 0) {
    a_src[n * HEADS + (t >> 5)] = ps;
    a_dst[n * HEADS + (t >> 5)] = pd;
  }
}

__global__ __launch_bounds__(64) void att_scores2(const float* __restrict__ h2,
    const float* __restrict__ asw, const float* __restrict__ adw,
    float* __restrict__ a_src, float* __restrict__ a_dst) {
  int n = blockIdx.x, c = threadIdx.x;
  float v  = h2[(size_t)n * CLS + c];
  float ps = v * asw[c];
  float pd = v * adw[c];
#pragma unroll
  for (int o = 32; o >= 1; o >>= 1) {
    ps += __shfl_xor(ps, o);
    pd += __shfl_xor(pd, o);
  }
  if (c == 0) { a_src[n] = ps; a_dst[n] = pd; }
}

// ---------------- CSR build (dst-indexed; self-loops implicit) ----------------
__global__ __launch_bounds__(256) void count_deg(const int* __restrict__ ei,
    int* __restrict__ deg, int E) {
  int e = blockIdx.x * 256 + threadIdx.x;
  if (e < E) atomicAdd(&deg[ei[E + e]], 1);
}

// single-block exclusive scan over deg[N] -> rowstart[N+1]
__global__ __launch_bounds__(1024) void scan_rows(const int* __restrict__ deg,
    int* __restrict__ rowstart, int N) {
  __shared__ int wpart[16];
  __shared__ int s_carry;
  const int t = threadIdx.x, lane = t & 63, wid = t >> 6;
  if (t == 0) s_carry = 0;
  __syncthreads();
  for (int base = 0; base < N; base += 8192) {
    int i0 = base + t * 8;
    int d0[8], s8 = 0;
#pragma unroll
    for (int k = 0; k < 8; k++) { int i = i0 + k; d0[k] = (i < N) ? deg[i] : 0; s8 += d0[k]; }
    int v = s8;
#pragma unroll
    for (int off = 1; off < 64; off <<= 1) { int x = __shfl_up(v, off); if (lane >= off) v += x; }
    if (lane == 63) wpart[wid] = v;
    __syncthreads();
    if (wid == 0) {
      int w = (lane < 16) ? wpart[lane] : 0;
#pragma unroll
      for (int off = 1; off < 16; off <<= 1) { int x = __shfl_up(w, off); if (lane >= off) w += x; }
      if (lane < 16) wpart[lane] = w;
    }
    __syncthreads();
    int excl = s_carry + (wid > 0 ? wpart[wid - 1] : 0) + v - s8;
#pragma unroll
    for (int k = 0; k < 8; k++) { int i = i0 + k; if (i < N) rowstart[i] = excl; excl += d0[k]; }
    __syncthreads();
    if (t == 0) s_carry += wpart[15];
    __syncthreads();
  }
  if (t == 0) rowstart[N] = s_carry;
}

__global__ __launch_bounds__(256) void scatter_csr(const int* __restrict__ ei,
    int* __restrict__ cur, int* __restrict__ csr_src, int E) {
  int e = blockIdx.x * 256 + threadIdx.x;
  if (e >= E) return;
  int s = ei[e], d = ei[E + e];
  int pos = atomicAdd(&cur[d], 1);
  csr_src[pos] = s;
}

// ---------------- layer-1 fused softmax+aggregate+bias+relu ----------------
// block 256 = one dest node; t -> channel; h = t>>5
__global__ __launch_bounds__(256) void gather1(const int* __restrict__ rowstart,
    const int* __restrict__ csr_src, const float* __restrict__ h1,
    const float* __restrict__ as1, const float* __restrict__ ad1,
    const float* __restrict__ b1, float* __restrict__ o1) {
  const int d = blockIdx.x;
  const int t = threadIdx.x;
  const int lane = t & 63, wid = t >> 6;
  __shared__ float sadd[8], sm[8], sinv[8], salf[8];
  __shared__ float wred[32];
  const int r0 = rowstart[d];
  const int deg = rowstart[d + 1] - r0;

  if (t < 8) sadd[t] = ad1[(size_t)d * 8 + t];
  __syncthreads();

  float self_sc = 0.f;
  if (t < 8) self_sc = leaky(as1[(size_t)d * 8 + t] + sadd[t]);

  // phase 1: per-head max.  t -> (edge slot = t>>3, head = t&7)
  const int h8 = t & 7;
  float vmax = -3.4e38f;
  for (int j = t >> 3; j < deg; j += 32) {
    int s = csr_src[r0 + j];
    vmax = fmaxf(vmax, leaky(as1[(size_t)s * 8 + h8] + sadd[h8]));
  }
#pragma unroll
  for (int o = 8; o <= 32; o <<= 1) vmax = fmaxf(vmax, __shfl_xor(vmax, o));
  if (lane < 8) wred[wid * 8 + h8] = vmax;
  __syncthreads();
  if (t < 8)
    sm[t] = fmaxf(fmaxf(fmaxf(wred[t], wred[8 + t]), fmaxf(wred[16 + t], wred[24 + t])), self_sc);
  __syncthreads();

  // phase 2: per-head sum of exp
  float vsum = 0.f;
  {
    const float mh = sm[h8];
    for (int j = t >> 3; j < deg; j += 32) {
      int s = csr_src[r0 + j];
      vsum += __expf(leaky(as1[(size_t)s * 8 + h8] + sadd[h8]) - mh);
    }
  }
#pragma unroll
  for (int o = 8; o <= 32; o <<= 1) vsum += __shfl_xor(vsum, o);
  if (lane < 8) wred[wid * 8 + h8] = vsum;
  __syncthreads();
  if (t < 8) {
    float es = __expf(self_sc - sm[t]);
    float tot = wred[t] + wred[8 + t] + wred[16 + t] + wred[24 + t] + es;
    float inv = 1.f / (tot + EPS);
    sinv[t] = inv;
    salf[t] = es * inv;
  }
  __syncthreads();

  // phase 3: aggregate.  t = channel, h = t>>5
  const int h = t >> 5;
  const float mh = sm[h], invh = sinv[h], addh = sadd[h];
  float acc = salf[h] * h1[(size_t)d * C1 + t];
  int j = 0;
  for (; j + 1 < deg; j += 2) {
    int s0 = csr_src[r0 + j];
    int s1 = csr_src[r0 + j + 1];
    float x0 = h1[(size_t)s0 * C1 + t];
    float x1 = h1[(size_t)s1 * C1 + t];
    float a0 = __expf(leaky(as1[(size_t)s0 * 8 + h] + addh) - mh) * invh;
    float a1 = __expf(leaky(as1[(size_t)s1 * 8 + h] + addh) - mh) * invh;
    acc += a0 * x0 + a1 * x1;
  }
  if (j < deg) {
    int s0 = csr_src[r0 + j];
    acc += __expf(leaky(as1[(size_t)s0 * 8 + h] + addh) - mh) * invh * h1[(size_t)s0 * C1 + t];
  }
  o1[(size_t)d * C1 + t] = fmaxf(acc + b1[t], 0.f);  // fused bias + relu
}

// ---------------- layer-2 fused softmax+aggregate+bias+log_softmax ----------------
// wave per node, 4 nodes per block; lane c = channel
__global__ __launch_bounds__(256) void gather2(const int* __restrict__ rowstart,
    const int* __restrict__ csr_src, const float* __restrict__ h2,
    const float* __restrict__ as2, const float* __restrict__ ad2,
    const float* __restrict__ b2, float* __restrict__ out, int N) {
  const int t = threadIdx.x;
  const int d = blockIdx.x * 4 + (t >> 6);
  const int c = t & 63;
  if (d >= N) return;
  const int r0 = rowstart[d];
  const int deg = rowstart[d + 1] - r0;
  const float add_d = ad2[d];
  const float self_sc = leaky(as2[d] + add_d);

  float mx = self_sc;
  for (int j = c; j < deg; j += 64)
    mx = fmaxf(mx, leaky(as2[csr_src[r0 + j]] + add_d));
#pragma unroll
  for (int o = 1; o < 64; o <<= 1) mx = fmaxf(mx, __shfl_xor(mx, o));

  float sum = 0.f;
  for (int j = c; j < deg; j += 64)
    sum += __expf(leaky(as2[csr_src[r0 + j]] + add_d) - mx);
#pragma unroll
  for (int o = 1; o < 64; o <<= 1) sum += __shfl_xor(sum, o);
  float es = __expf(self_sc - mx);
  sum += es;
  const float inv = 1.f / (sum + EPS);

  float acc = es * inv * h2[(size_t)d * CLS + c];
  int j = 0;
  for (; j + 1 < deg; j += 2) {
    int s0 = csr_src[r0 + j];
    int s1 = csr_src[r0 + j + 1];
    float x0 = h2[(size_t)s0 * CLS + c];
    float x1 = h2[(size_t)s1 * CLS + c];
    float a0 = __expf(leaky(as2[s0] + add_d) - mx) * inv;
    float a1 = __expf(leaky(as2[s1] + add_d) - mx) * inv;
    acc += a0 * x0 + a1 * x1;
  }
  if (j < deg) {
    int s0 = csr_src[r0 + j];
    acc += __expf(leaky(as2[s0] + add_d) - mx) * inv * h2[(size_t)s0 * CLS + c];
  }

  // fused bias + log_softmax over 64 classes
  float v = acc + b2[c];
  float m2 = v;
#pragma unroll
  for (int o = 1; o < 64; o <<= 1) m2 = fmaxf(m2, __shfl_xor(m2, o));
  float ex = __expf(v - m2);
  float sm = ex;
#pragma unroll
  for (int o = 1; o < 64; o <<= 1) sm += __shfl_xor(sm, o);
  out[(size_t)d * CLS + c] = v - m2 - __logf(sm);
}

extern "C" void kernel_launch(void* const* d_in, const int* in_sizes, int n_in,
                              void* d_out, int out_size, void* d_ws, size_t ws_size,
                              hipStream_t stream) {
  const float* x        = (const float*)d_in[0];
  const int*   ei       = (const int*)d_in[1];
  const float* W1       = (const float*)d_in[2];
  const float* att_src1 = (const float*)d_in[3];
  const float* att_dst1 = (const float*)d_in[4];
  const float* b1       = (const float*)d_in[5];
  const float* W2       = (const float*)d_in[6];
  const float* att_src2 = (const float*)d_in[7];
  const float* att_dst2 = (const float*)d_in[8];
  const float* b2       = (const float*)d_in[9];
  float* out = (float*)d_out;

  const int N  = in_sizes[0] / F_IN;   // 50000
  const int E  = in_sizes[1] / 2;      // 800000

  char* ws = (char*)d_ws;
  size_t off = 0;
  auto alloc = [&](size_t bytes) -> void* {
    void* p = ws + off;
    off += (bytes + 255) & ~(size_t)255;
    return p;
  };
  float* h1  = (float*)alloc((size_t)N * C1 * 4);
  float* o1  = (float*)alloc((size_t)N * C1 * 4);
  float* as1 = (float*)alloc((size_t)N * HEADS * 4);
  float* ad1 = (float*)alloc((size_t)N * HEADS * 4);
  float* h2  = (float*)alloc((size_t)N * CLS * 4);
  float* as2 = (float*)alloc((size_t)N * 4);
  float* ad2 = (float*)alloc((size_t)N * 4);
  int* deg      = (int*)alloc((size_t)N * 4);
  int* rowstart = (int*)alloc((size_t)(N + 1) * 4);
  int* cur      = (int*)alloc((size_t)N * 4);
  int* csr_src  = (int*)alloc((size_t)E * 4);

  // ---- CSR build (self-loops implicit in gather kernels) ----
  hipMemsetAsync(deg, 0, (size_t)N * 4, stream);
  count_deg<<<(E + 255) / 256, 256, 0, stream>>>(ei, deg, E);
  scan_rows<<<1, 1024, 0, stream>>>(deg, rowstart, N);
  hipMemcpyAsync(cur, rowstart, (size_t)N * 4, hipMemcpyDeviceToDevice, stream);
  scatter_csr<<<(E + 255) / 256, 256, 0, stream>>>(ei, cur, csr_src, E);

  // ---- layer 1 ----
  gemm_rt<C1, 32, 64><<<(N + 31) / 32, 256, 0, stream>>>(x, W1, h1, N, F_IN);
  att_scores1<<<N, 256, 0, stream>>>(h1, att_src1, att_dst1, as1, ad1);
  gather1<<<N, 256, 0, stream>>>(rowstart, csr_src, h1, as1, ad1, b1, o1);

  // ---- layer 2 ----
  gemm_rt<CLS, 64, 64><<<(N + 63) / 64, 256, 0, stream>>>(o1, W2, h2, N, C1);
  att_scores2<<<N, 64, 0, stream>>>(h2, att_src2, att_dst2, as2, ad2);
  gather2<<<(N + 3) / 4, 256, 0, stream>>>(rowstart, csr_src, h2, as2, ad2, b2, out, N);
}

// Round 3
// 700.301 us; speedup vs baseline: 3.2463x; 1.4518x over previous
//
#include <hip/hip_runtime.h>
#include <hip/hip_bf16.h>
#include <stdint.h>

#define F_IN 512
#define HID 32
#define HEADS 8
#define C1 (HEADS*HID)   // 256
#define CLS 64
#define NEG 0.2f
#define EPS 1e-16f

typedef __bf16 bf16x8 __attribute__((ext_vector_type(8)));
typedef float  f32x4  __attribute__((ext_vector_type(4)));

__device__ __forceinline__ float leaky(float v) { return v > 0.f ? v : NEG * v; }

// ---------------- fp32 -> bf16 conversions ----------------
__global__ __launch_bounds__(256) void cvt_x(const float* __restrict__ x,
    __bf16* __restrict__ xb, int total8) {  // total8 = total/8
  int i = blockIdx.x * 256 + threadIdx.x;
  if (i >= total8) return;
  const float4* p = (const float4*)(x + (size_t)i * 8);
  float4 a = p[0], b = p[1];
  bf16x8 o;
  o[0] = (__bf16)a.x; o[1] = (__bf16)a.y; o[2] = (__bf16)a.z; o[3] = (__bf16)a.w;
  o[4] = (__bf16)b.x; o[5] = (__bf16)b.y; o[6] = (__bf16)b.z; o[7] = (__bf16)b.w;
  *(bf16x8*)(xb + (size_t)i * 8) = o;
}

// W1[512][256] fp32 -> w1t[256][512] bf16
__global__ __launch_bounds__(256) void cvt_w1t(const float* __restrict__ W1,
    __bf16* __restrict__ w1t) {
  int i = blockIdx.x * 256 + threadIdx.x;   // 16384 threads, 8 outputs each
  int o0 = i * 8;
  int c = o0 >> 9, k0 = o0 & 511;
  bf16x8 o;
#pragma unroll
  for (int j = 0; j < 8; j++) o[j] = (__bf16)W1[(size_t)(k0 + j) * C1 + c];
  *(bf16x8*)(w1t + (size_t)o0) = o;
}

// ---------------- MFMA GEMM1: C[M,256] = A[M,512] @ W1, A/Bt bf16 ----------------
// BM=128, BN=128, BK=32; block 256 = 4 waves in 2x2; wave tile 64x64 (4x4 of 16x16)
__global__ __launch_bounds__(256) void gemm1_mfma(const __bf16* __restrict__ A,
    const __bf16* __restrict__ Bt,   // [256][512]
    float* __restrict__ C, int M) {
  __shared__ __bf16 Al[128 * 32];
  __shared__ __bf16 Bl[128 * 32];
  const int tid  = threadIdx.x;
  const int lane = tid & 63;
  const int wave = tid >> 6;
  const int lm = lane & 15, q = lane >> 4;
  const int wr = (wave >> 1) * 64, wc = (wave & 1) * 64;
  const int bm = blockIdx.y * 128, bn = blockIdx.x * 128;

  const int srow = tid >> 2;            // staging row 0..63
  const int skc  = (tid & 3) * 8;       // staging k offset (elements)

  f32x4 acc[4][4];
#pragma unroll
  for (int i = 0; i < 4; i++)
#pragma unroll
    for (int j = 0; j < 4; j++) acc[i][j] = (f32x4){0.f, 0.f, 0.f, 0.f};

  const int ra0 = min(bm + srow, M - 1);
  const int ra1 = min(bm + srow + 64, M - 1);
  const int rb0 = bn + srow, rb1 = bn + srow + 64;

  bf16x8 va0, va1, vb0, vb1;
  va0 = *(const bf16x8*)(A + (size_t)ra0 * 512 + skc);
  va1 = *(const bf16x8*)(A + (size_t)ra1 * 512 + skc);
  vb0 = *(const bf16x8*)(Bt + (size_t)rb0 * 512 + skc);
  vb1 = *(const bf16x8*)(Bt + (size_t)rb1 * 512 + skc);

  for (int kk = 0; kk < 16; kk++) {
    __syncthreads();
    *(bf16x8*)(Al + srow * 32 + skc)        = va0;
    *(bf16x8*)(Al + (srow + 64) * 32 + skc) = va1;
    *(bf16x8*)(Bl + srow * 32 + skc)        = vb0;
    *(bf16x8*)(Bl + (srow + 64) * 32 + skc) = vb1;
    __syncthreads();
    if (kk + 1 < 16) {
      const int k0 = (kk + 1) * 32;
      va0 = *(const bf16x8*)(A + (size_t)ra0 * 512 + k0 + skc);
      va1 = *(const bf16x8*)(A + (size_t)ra1 * 512 + k0 + skc);
      vb0 = *(const bf16x8*)(Bt + (size_t)rb0 * 512 + k0 + skc);
      vb1 = *(const bf16x8*)(Bt + (size_t)rb1 * 512 + k0 + skc);
    }
    bf16x8 af[4], bfr[4];
#pragma unroll
    for (int mi = 0; mi < 4; mi++)
      af[mi] = *(const bf16x8*)(Al + (wr + mi * 16 + lm) * 32 + q * 8);
#pragma unroll
    for (int ni = 0; ni < 4; ni++)
      bfr[ni] = *(const bf16x8*)(Bl + (wc + ni * 16 + lm) * 32 + q * 8);
#pragma unroll
    for (int mi = 0; mi < 4; mi++)
#pragma unroll
      for (int ni = 0; ni < 4; ni++)
        acc[mi][ni] = __builtin_amdgcn_mfma_f32_16x16x32_bf16(af[mi], bfr[ni], acc[mi][ni], 0, 0, 0);
  }

#pragma unroll
  for (int mi = 0; mi < 4; mi++) {
#pragma unroll
    for (int ni = 0; ni < 4; ni++) {
      const int col = bn + wc + ni * 16 + lm;
#pragma unroll
      for (int r = 0; r < 4; r++) {
        const int row = bm + wr + mi * 16 + q * 4 + r;
        if (row < M) C[(size_t)row * C1 + col] = acc[mi][ni][r];
      }
    }
  }
}

// ---------------- fp32 GEMM (layer 2) ----------------
template<int NCOLS, int ROWS, int KT>
__global__ __launch_bounds__(256) void gemm_rt(const float* __restrict__ A,
                                               const float* __restrict__ B,
                                               float* __restrict__ C, int M, int K) {
  __shared__ float At[ROWS][KT];
  constexpr int RPT = ROWS * NCOLS / 256;
  const int t   = threadIdx.x;
  const int r0  = blockIdx.x * ROWS;
  const int col = t % NCOLS;
  const int rg  = t / NCOLS;
  float acc[RPT];
#pragma unroll
  for (int i = 0; i < RPT; i++) acc[i] = 0.f;

  for (int k0 = 0; k0 < K; k0 += KT) {
    for (int idx = t; idx < ROWS * KT; idx += 256) {
      int rr = idx / KT, kk = idx % KT;
      int r = r0 + rr;
      At[rr][kk] = (r < M) ? A[(size_t)r * K + (k0 + kk)] : 0.f;
    }
    __syncthreads();
    for (int k = 0; k < KT; k += 4) {
      float b0 = B[(size_t)(k0 + k) * NCOLS + col];
      float b1 = B[(size_t)(k0 + k + 1) * NCOLS + col];
      float b2 = B[(size_t)(k0 + k + 2) * NCOLS + col];
      float b3 = B[(size_t)(k0 + k + 3) * NCOLS + col];
#pragma unroll
      for (int i = 0; i < RPT; i++) {
        const float4 a4 = *(const float4*)&At[rg * RPT + i][k];
        acc[i] += a4.x * b0 + a4.y * b1 + a4.z * b2 + a4.w * b3;
      }
    }
    __syncthreads();
  }
#pragma unroll
  for (int i = 0; i < RPT; i++) {
    int r = r0 + rg * RPT + i;
    if (r < M) C[(size_t)r * NCOLS + col] = acc[i];
  }
}

// ---------------- attention score dots ----------------
__global__ __launch_bounds__(256) void att_scores1(const float* __restrict__ h1,
    const float* __restrict__ asw, const float* __restrict__ adw,
    float* __restrict__ a_src, float* __restrict__ a_dst) {
  int n = blockIdx.x, t = threadIdx.x;
  float v  = h1[(size_t)n * C1 + t];
  float ps = v * asw[t];
  float pd = v * adw[t];
#pragma unroll
  for (int o = 16; o >= 1; o >>= 1) {
    ps += __shfl_xor(ps, o);
    pd += __shfl_xor(pd, o);
  }
  if ((t & 31) == 0) {
    a_src[n * HEADS + (t >> 5)] = ps;
    a_dst[n * HEADS + (t >> 5)] = pd;
  }
}

__global__ __launch_bounds__(64) void att_scores2(const float* __restrict__ h2,
    const float* __restrict__ asw, const float* __restrict__ adw,
    float* __restrict__ a_src, float* __restrict__ a_dst) {
  int n = blockIdx.x, c = threadIdx.x;
  float v  = h2[(size_t)n * CLS + c];
  float ps = v * asw[c];
  float pd = v * adw[c];
#pragma unroll
  for (int o = 32; o >= 1; o >>= 1) {
    ps += __shfl_xor(ps, o);
    pd += __shfl_xor(pd, o);
  }
  if (c == 0) { a_src[n] = ps; a_dst[n] = pd; }
}

// ---------------- CSR build (dst-indexed; self-loops implicit) ----------------
__global__ __launch_bounds__(256) void count_deg(const int* __restrict__ ei,
    int* __restrict__ deg, int E) {
  int e = blockIdx.x * 256 + threadIdx.x;
  if (e < E) atomicAdd(&deg[ei[E + e]], 1);
}

__global__ __launch_bounds__(1024) void scan_rows(const int* __restrict__ deg,
    int* __restrict__ rowstart, int N) {
  __shared__ int wpart[16];
  __shared__ int s_carry;
  const int t = threadIdx.x, lane = t & 63, wid = t >> 6;
  if (t == 0) s_carry = 0;
  __syncthreads();
  for (int base = 0; base < N; base += 8192) {
    int i0 = base + t * 8;
    int d0[8], s8 = 0;
#pragma unroll
    for (int k = 0; k < 8; k++) { int i = i0 + k; d0[k] = (i < N) ? deg[i] : 0; s8 += d0[k]; }
    int v = s8;
#pragma unroll
    for (int off = 1; off < 64; off <<= 1) { int x = __shfl_up(v, off); if (lane >= off) v += x; }
    if (lane == 63) wpart[wid] = v;
    __syncthreads();
    if (wid == 0) {
      int w = (lane < 16) ? wpart[lane] : 0;
#pragma unroll
      for (int off = 1; off < 16; off <<= 1) { int x = __shfl_up(w, off); if (lane >= off) w += x; }
      if (lane < 16) wpart[lane] = w;
    }
    __syncthreads();
    int excl = s_carry + (wid > 0 ? wpart[wid - 1] : 0) + v - s8;
#pragma unroll
    for (int k = 0; k < 8; k++) { int i = i0 + k; if (i < N) rowstart[i] = excl; excl += d0[k]; }
    __syncthreads();
    if (t == 0) s_carry += wpart[15];
    __syncthreads();
  }
  if (t == 0) rowstart[N] = s_carry;
}

__global__ __launch_bounds__(256) void scatter_csr(const int* __restrict__ ei,
    int* __restrict__ cur, int* __restrict__ csr_src, int E) {
  int e = blockIdx.x * 256 + threadIdx.x;
  if (e >= E) return;
  int s = ei[e], d = ei[E + e];
  int pos = atomicAdd(&cur[d], 1);
  csr_src[pos] = s;
}

// ---------------- layer-1 fused softmax+aggregate+bias+relu ----------------
__global__ __launch_bounds__(256) void gather1(const int* __restrict__ rowstart,
    const int* __restrict__ csr_src, const float* __restrict__ h1,
    const float* __restrict__ as1, const float* __restrict__ ad1,
    const float* __restrict__ b1, float* __restrict__ o1) {
  const int d = blockIdx.x;
  const int t = threadIdx.x;
  const int lane = t & 63, wid = t >> 6;
  __shared__ float sadd[8], sm[8], sinv[8], salf[8];
  __shared__ float wred[32];
  const int r0 = rowstart[d];
  const int deg = rowstart[d + 1] - r0;

  if (t < 8) sadd[t] = ad1[(size_t)d * 8 + t];
  __syncthreads();

  float self_sc = 0.f;
  if (t < 8) self_sc = leaky(as1[(size_t)d * 8 + t] + sadd[t]);

  const int h8 = t & 7;
  float vmax = -3.4e38f;
  for (int j = t >> 3; j < deg; j += 32) {
    int s = csr_src[r0 + j];
    vmax = fmaxf(vmax, leaky(as1[(size_t)s * 8 + h8] + sadd[h8]));
  }
#pragma unroll
  for (int o = 8; o <= 32; o <<= 1) vmax = fmaxf(vmax, __shfl_xor(vmax, o));
  if (lane < 8) wred[wid * 8 + h8] = vmax;
  __syncthreads();
  if (t < 8)
    sm[t] = fmaxf(fmaxf(fmaxf(wred[t], wred[8 + t]), fmaxf(wred[16 + t], wred[24 + t])), self_sc);
  __syncthreads();

  float vsum = 0.f;
  {
    const float mh = sm[h8];
    for (int j = t >> 3; j < deg; j += 32) {
      int s = csr_src[r0 + j];
      vsum += __expf(leaky(as1[(size_t)s * 8 + h8] + sadd[h8]) - mh);
    }
  }
#pragma unroll
  for (int o = 8; o <= 32; o <<= 1) vsum += __shfl_xor(vsum, o);
  if (lane < 8) wred[wid * 8 + h8] = vsum;
  __syncthreads();
  if (t < 8) {
    float es = __expf(self_sc - sm[t]);
    float tot = wred[t] + wred[8 + t] + wred[16 + t] + wred[24 + t] + es;
    float inv = 1.f / (tot + EPS);
    sinv[t] = inv;
    salf[t] = es * inv;
  }
  __syncthreads();

  const int h = t >> 5;
  const float mh = sm[h], invh = sinv[h], addh = sadd[h];
  float acc = salf[h] * h1[(size_t)d * C1 + t];
  int j = 0;
  for (; j + 1 < deg; j += 2) {
    int s0 = csr_src[r0 + j];
    int s1 = csr_src[r0 + j + 1];
    float x0 = h1[(size_t)s0 * C1 + t];
    float x1 = h1[(size_t)s1 * C1 + t];
    float a0 = __expf(leaky(as1[(size_t)s0 * 8 + h] + addh) - mh) * invh;
    float a1 = __expf(leaky(as1[(size_t)s1 * 8 + h] + addh) - mh) * invh;
    acc += a0 * x0 + a1 * x1;
  }
  if (j < deg) {
    int s0 = csr_src[r0 + j];
    acc += __expf(leaky(as1[(size_t)s0 * 8 + h] + addh) - mh) * invh * h1[(size_t)s0 * C1 + t];
  }
  o1[(size_t)d * C1 + t] = fmaxf(acc + b1[t], 0.f);
}

// ---------------- layer-2 fused softmax+aggregate+bias+log_softmax ----------------
__global__ __launch_bounds__(256) void gather2(const int* __restrict__ rowstart,
    const int* __restrict__ csr_src, const float* __restrict__ h2,
    const float* __restrict__ as2, const float* __restrict__ ad2,
    const float* __restrict__ b2, float* __restrict__ out, int N) {
  const int t = threadIdx.x;
  const int d = blockIdx.x * 4 + (t >> 6);
  const int c = t & 63;
  if (d >= N) return;
  const int r0 = rowstart[d];
  const int deg = rowstart[d + 1] - r0;
  const float add_d = ad2[d];
  const float self_sc = leaky(as2[d] + add_d);

  float mx = self_sc;
  for (int j = c; j < deg; j += 64)
    mx = fmaxf(mx, leaky(as2[csr_src[r0 + j]] + add_d));
#pragma unroll
  for (int o = 1; o < 64; o <<= 1) mx = fmaxf(mx, __shfl_xor(mx, o));

  float sum = 0.f;
  for (int j = c; j < deg; j += 64)
    sum += __expf(leaky(as2[csr_src[r0 + j]] + add_d) - mx);
#pragma unroll
  for (int o = 1; o < 64; o <<= 1) sum += __shfl_xor(sum, o);
  float es = __expf(self_sc - mx);
  sum += es;
  const float inv = 1.f / (sum + EPS);

  float acc = es * inv * h2[(size_t)d * CLS + c];
  int j = 0;
  for (; j + 1 < deg; j += 2) {
    int s0 = csr_src[r0 + j];
    int s1 = csr_src[r0 + j + 1];
    float x0 = h2[(size_t)s0 * CLS + c];
    float x1 = h2[(size_t)s1 * CLS + c];
    float a0 = __expf(leaky(as2[s0] + add_d) - mx) * inv;
    float a1 = __expf(leaky(as2[s1] + add_d) - mx) * inv;
    acc += a0 * x0 + a1 * x1;
  }
  if (j < deg) {
    int s0 = csr_src[r0 + j];
    acc += __expf(leaky(as2[s0] + add_d) - mx) * inv * h2[(size_t)s0 * CLS + c];
  }

  float v = acc + b2[c];
  float m2 = v;
#pragma unroll
  for (int o = 1; o < 64; o <<= 1) m2 = fmaxf(m2, __shfl_xor(m2, o));
  float ex = __expf(v - m2);
  float sm = ex;
#pragma unroll
  for (int o = 1; o < 64; o <<= 1) sm += __shfl_xor(sm, o);
  out[(size_t)d * CLS + c] = v - m2 - __logf(sm);
}

extern "C" void kernel_launch(void* const* d_in, const int* in_sizes, int n_in,
                              void* d_out, int out_size, void* d_ws, size_t ws_size,
                              hipStream_t stream) {
  const float* x        = (const float*)d_in[0];
  const int*   ei       = (const int*)d_in[1];
  const float* W1       = (const float*)d_in[2];
  const float* att_src1 = (const float*)d_in[3];
  const float* att_dst1 = (const float*)d_in[4];
  const float* b1       = (const float*)d_in[5];
  const float* W2       = (const float*)d_in[6];
  const float* att_src2 = (const float*)d_in[7];
  const float* att_dst2 = (const float*)d_in[8];
  const float* b2       = (const float*)d_in[9];
  float* out = (float*)d_out;

  const int N  = in_sizes[0] / F_IN;   // 50000
  const int E  = in_sizes[1] / 2;      // 800000

  char* ws = (char*)d_ws;
  size_t off = 0;
  auto alloc = [&](size_t bytes) -> void* {
    void* p = ws + off;
    off += (bytes + 255) & ~(size_t)255;
    return p;
  };
  float*  h1  = (float*)alloc((size_t)N * C1 * 4);
  float*  o1  = (float*)alloc((size_t)N * C1 * 4);
  float*  as1 = (float*)alloc((size_t)N * HEADS * 4);
  float*  ad1 = (float*)alloc((size_t)N * HEADS * 4);
  float*  h2  = (float*)alloc((size_t)N * CLS * 4);
  float*  as2 = (float*)alloc((size_t)N * 4);
  float*  ad2 = (float*)alloc((size_t)N * 4);
  int* deg      = (int*)alloc((size_t)N * 4);
  int* rowstart = (int*)alloc((size_t)(N + 1) * 4);
  int* cur      = (int*)alloc((size_t)N * 4);
  int* csr_src  = (int*)alloc((size_t)E * 4);
  __bf16* xb  = (__bf16*)alloc((size_t)N * F_IN * 2);
  __bf16* w1t = (__bf16*)alloc((size_t)C1 * F_IN * 2);

  // ---- bf16 conversions ----
  cvt_x<<<(N * F_IN / 8 + 255) / 256, 256, 0, stream>>>(x, xb, N * F_IN / 8);
  cvt_w1t<<<(C1 * F_IN / 8 + 255) / 256, 256, 0, stream>>>(W1, w1t);

  // ---- CSR build (self-loops implicit in gather kernels) ----
  hipMemsetAsync(deg, 0, (size_t)N * 4, stream);
  count_deg<<<(E + 255) / 256, 256, 0, stream>>>(ei, deg, E);
  scan_rows<<<1, 1024, 0, stream>>>(deg, rowstart, N);
  hipMemcpyAsync(cur, rowstart, (size_t)N * 4, hipMemcpyDeviceToDevice, stream);
  scatter_csr<<<(E + 255) / 256, 256, 0, stream>>>(ei, cur, csr_src, E);

  // ---- layer 1 ----
  {
    dim3 g(C1 / 128, (N + 127) / 128);
    gemm1_mfma<<<g, 256, 0, stream>>>(xb, w1t, h1, N);
  }
  att_scores1<<<N, 256, 0, stream>>>(h1, att_src1, att_dst1, as1, ad1);
  gather1<<<N, 256, 0, stream>>>(rowstart, csr_src, h1, as1, ad1, b1, o1);

  // ---- layer 2 ----
  gemm_rt<CLS, 64, 64><<<(N + 63) / 64, 256, 0, stream>>>(o1, W2, h2, N, C1);
  att_scores2<<<N, 64, 0, stream>>>(h2, att_src2, att_dst2, as2, ad2);
  gather2<<<(N + 3) / 4, 256, 0, stream>>>(rowstart, csr_src, h2, as2, ad2, b2, out, N);
}

// Round 4
// 642.065 us; speedup vs baseline: 3.5407x; 1.0907x over previous
//
#include <hip/hip_runtime.h>
#include <hip/hip_bf16.h>
#include <stdint.h>

#define F_IN 512
#define HID 32
#define HEADS 8
#define C1 (HEADS*HID)   // 256
#define CLS 64
#define NEG 0.2f
#define EPS 1e-16f

typedef __bf16 bf16x8 __attribute__((ext_vector_type(8)));
typedef float  f32x4  __attribute__((ext_vector_type(4)));

__device__ __forceinline__ float leaky(float v) { return v > 0.f ? v : NEG * v; }

// ---------------- fp32 -> bf16 conversions ----------------
__global__ __launch_bounds__(256) void cvt_x(const float* __restrict__ x,
    __bf16* __restrict__ xb, int total8) {
  int i = blockIdx.x * 256 + threadIdx.x;
  if (i >= total8) return;
  const float4* p = (const float4*)(x + (size_t)i * 8);
  float4 a = p[0], b = p[1];
  bf16x8 o;
  o[0] = (__bf16)a.x; o[1] = (__bf16)a.y; o[2] = (__bf16)a.z; o[3] = (__bf16)a.w;
  o[4] = (__bf16)b.x; o[5] = (__bf16)b.y; o[6] = (__bf16)b.z; o[7] = (__bf16)b.w;
  *(bf16x8*)(xb + (size_t)i * 8) = o;
}

// W1[512][256] fp32 -> w1t[256][512] bf16
__global__ __launch_bounds__(256) void cvt_w1t(const float* __restrict__ W1,
    __bf16* __restrict__ w1t) {
  int i = blockIdx.x * 256 + threadIdx.x;
  int o0 = i * 8;
  int c = o0 >> 9, k0 = o0 & 511;
  bf16x8 o;
#pragma unroll
  for (int j = 0; j < 8; j++) o[j] = (__bf16)W1[(size_t)(k0 + j) * C1 + c];
  *(bf16x8*)(w1t + (size_t)o0) = o;
}

// W2[256][64] fp32 -> w2t[64][256] bf16   (2048 threads)
__global__ __launch_bounds__(256) void cvt_w2t(const float* __restrict__ W2,
    __bf16* __restrict__ w2t) {
  int i = blockIdx.x * 256 + threadIdx.x;
  if (i >= CLS * C1 / 8) return;
  int o0 = i * 8;
  int c = o0 >> 8, k0 = o0 & 255;
  bf16x8 o;
#pragma unroll
  for (int j = 0; j < 8; j++) o[j] = (__bf16)W2[(size_t)(k0 + j) * CLS + c];
  *(bf16x8*)(w2t + (size_t)o0) = o;
}

// ---------------- MFMA GEMM1: h1[M,256] = xb[M,512] @ w1t^T, out bf16 ----------------
__global__ __launch_bounds__(256) void gemm1_mfma(const __bf16* __restrict__ A,
    const __bf16* __restrict__ Bt, __bf16* __restrict__ C, int M) {
  __shared__ __bf16 Al[128 * 32];
  __shared__ __bf16 Bl[128 * 32];
  const int tid  = threadIdx.x;
  const int lane = tid & 63;
  const int wave = tid >> 6;
  const int lm = lane & 15, q = lane >> 4;
  const int wr = (wave >> 1) * 64, wc = (wave & 1) * 64;
  const int bm = blockIdx.y * 128, bn = blockIdx.x * 128;

  const int srow = tid >> 2;
  const int skc  = (tid & 3) * 8;

  f32x4 acc[4][4];
#pragma unroll
  for (int i = 0; i < 4; i++)
#pragma unroll
    for (int j = 0; j < 4; j++) acc[i][j] = (f32x4){0.f, 0.f, 0.f, 0.f};

  const int ra0 = min(bm + srow, M - 1);
  const int ra1 = min(bm + srow + 64, M - 1);
  const int rb0 = bn + srow, rb1 = bn + srow + 64;

  bf16x8 va0, va1, vb0, vb1;
  va0 = *(const bf16x8*)(A + (size_t)ra0 * 512 + skc);
  va1 = *(const bf16x8*)(A + (size_t)ra1 * 512 + skc);
  vb0 = *(const bf16x8*)(Bt + (size_t)rb0 * 512 + skc);
  vb1 = *(const bf16x8*)(Bt + (size_t)rb1 * 512 + skc);

  for (int kk = 0; kk < 16; kk++) {
    __syncthreads();
    *(bf16x8*)(Al + srow * 32 + skc)        = va0;
    *(bf16x8*)(Al + (srow + 64) * 32 + skc) = va1;
    *(bf16x8*)(Bl + srow * 32 + skc)        = vb0;
    *(bf16x8*)(Bl + (srow + 64) * 32 + skc) = vb1;
    __syncthreads();
    if (kk + 1 < 16) {
      const int k0 = (kk + 1) * 32;
      va0 = *(const bf16x8*)(A + (size_t)ra0 * 512 + k0 + skc);
      va1 = *(const bf16x8*)(A + (size_t)ra1 * 512 + k0 + skc);
      vb0 = *(const bf16x8*)(Bt + (size_t)rb0 * 512 + k0 + skc);
      vb1 = *(const bf16x8*)(Bt + (size_t)rb1 * 512 + k0 + skc);
    }
    bf16x8 af[4], bfr[4];
#pragma unroll
    for (int mi = 0; mi < 4; mi++)
      af[mi] = *(const bf16x8*)(Al + (wr + mi * 16 + lm) * 32 + q * 8);
#pragma unroll
    for (int ni = 0; ni < 4; ni++)
      bfr[ni] = *(const bf16x8*)(Bl + (wc + ni * 16 + lm) * 32 + q * 8);
#pragma unroll
    for (int mi = 0; mi < 4; mi++)
#pragma unroll
      for (int ni = 0; ni < 4; ni++)
        acc[mi][ni] = __builtin_amdgcn_mfma_f32_16x16x32_bf16(af[mi], bfr[ni], acc[mi][ni], 0, 0, 0);
  }

#pragma unroll
  for (int mi = 0; mi < 4; mi++) {
#pragma unroll
    for (int ni = 0; ni < 4; ni++) {
      const int col = bn + wc + ni * 16 + lm;
#pragma unroll
      for (int r = 0; r < 4; r++) {
        const int row = bm + wr + mi * 16 + q * 4 + r;
        if (row < M) C[(size_t)row * C1 + col] = (__bf16)acc[mi][ni][r];
      }
    }
  }
}

// ---------------- MFMA GEMM2: h2[M,64] = o1[M,256] @ w2t^T, out fp32 ----------------
__global__ __launch_bounds__(256) void gemm2_mfma(const __bf16* __restrict__ A,
    const __bf16* __restrict__ Bt, float* __restrict__ C, int M) {
  __shared__ __bf16 Al[128 * 32];
  __shared__ __bf16 Bl[64 * 32];
  const int tid  = threadIdx.x;
  const int lane = tid & 63;
  const int wave = tid >> 6;
  const int lm = lane & 15, q = lane >> 4;
  const int wr = (wave >> 1) * 64, wc = (wave & 1) * 32;
  const int bm = blockIdx.x * 128;

  const int srow = tid >> 2;
  const int skc  = (tid & 3) * 8;

  f32x4 acc[4][2];
#pragma unroll
  for (int i = 0; i < 4; i++)
#pragma unroll
    for (int j = 0; j < 2; j++) acc[i][j] = (f32x4){0.f, 0.f, 0.f, 0.f};

  const int ra0 = min(bm + srow, M - 1);
  const int ra1 = min(bm + srow + 64, M - 1);

  bf16x8 va0, va1, vb;
  va0 = *(const bf16x8*)(A + (size_t)ra0 * C1 + skc);
  va1 = *(const bf16x8*)(A + (size_t)ra1 * C1 + skc);
  vb  = *(const bf16x8*)(Bt + (size_t)srow * C1 + skc);

  for (int kk = 0; kk < 8; kk++) {
    __syncthreads();
    *(bf16x8*)(Al + srow * 32 + skc)        = va0;
    *(bf16x8*)(Al + (srow + 64) * 32 + skc) = va1;
    *(bf16x8*)(Bl + srow * 32 + skc)        = vb;
    __syncthreads();
    if (kk + 1 < 8) {
      const int k0 = (kk + 1) * 32;
      va0 = *(const bf16x8*)(A + (size_t)ra0 * C1 + k0 + skc);
      va1 = *(const bf16x8*)(A + (size_t)ra1 * C1 + k0 + skc);
      vb  = *(const bf16x8*)(Bt + (size_t)srow * C1 + k0 + skc);
    }
    bf16x8 af[4], bfr[2];
#pragma unroll
    for (int mi = 0; mi < 4; mi++)
      af[mi] = *(const bf16x8*)(Al + (wr + mi * 16 + lm) * 32 + q * 8);
#pragma unroll
    for (int ni = 0; ni < 2; ni++)
      bfr[ni] = *(const bf16x8*)(Bl + (wc + ni * 16 + lm) * 32 + q * 8);
#pragma unroll
    for (int mi = 0; mi < 4; mi++)
#pragma unroll
      for (int ni = 0; ni < 2; ni++)
        acc[mi][ni] = __builtin_amdgcn_mfma_f32_16x16x32_bf16(af[mi], bfr[ni], acc[mi][ni], 0, 0, 0);
  }

#pragma unroll
  for (int mi = 0; mi < 4; mi++) {
#pragma unroll
    for (int ni = 0; ni < 2; ni++) {
      const int col = wc + ni * 16 + lm;
#pragma unroll
      for (int r = 0; r < 4; r++) {
        const int row = bm + wr + mi * 16 + q * 4 + r;
        if (row < M) C[(size_t)row * CLS + col] = acc[mi][ni][r];
      }
    }
  }
}

// ---------------- attention score dots ----------------
__global__ __launch_bounds__(256) void att_scores1(const __bf16* __restrict__ h1,
    const float* __restrict__ asw, const float* __restrict__ adw,
    float* __restrict__ a_src, float* __restrict__ a_dst) {
  int n = blockIdx.x, t = threadIdx.x;
  float v  = (float)h1[(size_t)n * C1 + t];
  float ps = v * asw[t];
  float pd = v * adw[t];
#pragma unroll
  for (int o = 16; o >= 1; o >>= 1) {
    ps += __shfl_xor(ps, o);
    pd += __shfl_xor(pd, o);
  }
  if ((t & 31) == 0) {
    a_src[n * HEADS + (t >> 5)] = ps;
    a_dst[n * HEADS + (t >> 5)] = pd;
  }
}

__global__ __launch_bounds__(64) void att_scores2(const float* __restrict__ h2,
    const float* __restrict__ asw, const float* __restrict__ adw,
    float* __restrict__ a_src, float* __restrict__ a_dst) {
  int n = blockIdx.x, c = threadIdx.x;
  float v  = h2[(size_t)n * CLS + c];
  float ps = v * asw[c];
  float pd = v * adw[c];
#pragma unroll
  for (int o = 32; o >= 1; o >>= 1) {
    ps += __shfl_xor(ps, o);
    pd += __shfl_xor(pd, o);
  }
  if (c == 0) { a_src[n] = ps; a_dst[n] = pd; }
}

// ---------------- CSR build (dst-indexed; self-loops implicit) ----------------
__global__ __launch_bounds__(256) void count_deg(const int* __restrict__ ei,
    int* __restrict__ deg, int E) {
  int e = blockIdx.x * 256 + threadIdx.x;
  if (e < E) atomicAdd(&deg[ei[E + e]], 1);
}

__global__ __launch_bounds__(1024) void scan_rows(const int* __restrict__ deg,
    int* __restrict__ rowstart, int N) {
  __shared__ int wpart[16];
  __shared__ int s_carry;
  const int t = threadIdx.x, lane = t & 63, wid = t >> 6;
  if (t == 0) s_carry = 0;
  __syncthreads();
  for (int base = 0; base < N; base += 8192) {
    int i0 = base + t * 8;
    int d0[8], s8 = 0;
#pragma unroll
    for (int k = 0; k < 8; k++) { int i = i0 + k; d0[k] = (i < N) ? deg[i] : 0; s8 += d0[k]; }
    int v = s8;
#pragma unroll
    for (int off = 1; off < 64; off <<= 1) { int x = __shfl_up(v, off); if (lane >= off) v += x; }
    if (lane == 63) wpart[wid] = v;
    __syncthreads();
    if (wid == 0) {
      int w = (lane < 16) ? wpart[lane] : 0;
#pragma unroll
      for (int off = 1; off < 16; off <<= 1) { int x = __shfl_up(w, off); if (lane >= off) w += x; }
      if (lane < 16) wpart[lane] = w;
    }
    __syncthreads();
    int excl = s_carry + (wid > 0 ? wpart[wid - 1] : 0) + v - s8;
#pragma unroll
    for (int k = 0; k < 8; k++) { int i = i0 + k; if (i < N) rowstart[i] = excl; excl += d0[k]; }
    __syncthreads();
    if (t == 0) s_carry += wpart[15];
    __syncthreads();
  }
  if (t == 0) rowstart[N] = s_carry;
}

__global__ __launch_bounds__(256) void scatter_csr(const int* __restrict__ ei,
    int* __restrict__ cur, int* __restrict__ csr_src, int E) {
  int e = blockIdx.x * 256 + threadIdx.x;
  if (e >= E) return;
  int s = ei[e], d = ei[E + e];
  int pos = atomicAdd(&cur[d], 1);
  csr_src[pos] = s;
}

// ---------------- layer-1 fused softmax+aggregate+bias+relu ----------------
// block 256 = one dest node
__global__ __launch_bounds__(256) void gather1(const int* __restrict__ rowstart,
    const int* __restrict__ csr_src, const __bf16* __restrict__ h1,
    const float* __restrict__ as1, const float* __restrict__ ad1,
    const float* __restrict__ b1, __bf16* __restrict__ o1) {
  const int d = blockIdx.x;
  const int t = threadIdx.x;
  const int lane = t & 63, wid = t >> 6;
  __shared__ float sadd[8], sm[8], sinv[8], salf[8];
  __shared__ float wred[32];
  __shared__ float alf[32][8];
  __shared__ int   sedge[32];
  const int r0 = rowstart[d];
  const int deg = rowstart[d + 1] - r0;

  if (t < 8) sadd[t] = ad1[(size_t)d * 8 + t];
  __syncthreads();

  float self_sc = 0.f;
  if (t < 8) self_sc = leaky(as1[(size_t)d * 8 + t] + sadd[t]);

  // phase 1: per-head max.  t -> (edge slot = t>>3, head = t&7)
  const int h8 = t & 7;
  float vmax = -3.4e38f;
  for (int j = t >> 3; j < deg; j += 32) {
    int s = csr_src[r0 + j];
    vmax = fmaxf(vmax, leaky(as1[(size_t)s * 8 + h8] + sadd[h8]));
  }
#pragma unroll
  for (int o = 8; o <= 32; o <<= 1) vmax = fmaxf(vmax, __shfl_xor(vmax, o));
  if (lane < 8) wred[wid * 8 + h8] = vmax;
  __syncthreads();
  if (t < 8)
    sm[t] = fmaxf(fmaxf(fmaxf(wred[t], wred[8 + t]), fmaxf(wred[16 + t], wred[24 + t])), self_sc);
  __syncthreads();

  // phase 2: per-head sum of exp
  float vsum = 0.f;
  {
    const float mh = sm[h8];
    for (int j = t >> 3; j < deg; j += 32) {
      int s = csr_src[r0 + j];
      vsum += __expf(leaky(as1[(size_t)s * 8 + h8] + sadd[h8]) - mh);
    }
  }
#pragma unroll
  for (int o = 8; o <= 32; o <<= 1) vsum += __shfl_xor(vsum, o);
  if (lane < 8) wred[wid * 8 + h8] = vsum;
  __syncthreads();
  if (t < 8) {
    float es = __expf(self_sc - sm[t]);
    float tot = wred[t] + wred[8 + t] + wred[16 + t] + wred[24 + t] + es;
    float inv = 1.f / (tot + EPS);
    sinv[t] = inv;
    salf[t] = es * inv;
  }
  __syncthreads();

  // phase 3: LDS-staged alphas, 32-edge chunks
  const int h = t >> 5;
  float acc = salf[h] * (float)h1[(size_t)d * C1 + t];
  for (int c0 = 0; c0 < deg; c0 += 32) {
    const int j  = t >> 3;
    const int jj = c0 + j;
    if (jj < deg) {
      int s = csr_src[r0 + jj];
      if (h8 == 0) sedge[j] = s;
      alf[j][h8] = __expf(leaky(as1[(size_t)s * 8 + h8] + sadd[h8]) - sm[h8]) * sinv[h8];
    }
    __syncthreads();
    const int lim = min(32, deg - c0);
    int j2 = 0;
    for (; j2 + 1 < lim; j2 += 2) {
      float a0 = alf[j2][h],   a1 = alf[j2 + 1][h];
      float x0 = (float)h1[(size_t)sedge[j2] * C1 + t];
      float x1 = (float)h1[(size_t)sedge[j2 + 1] * C1 + t];
      acc += a0 * x0 + a1 * x1;
    }
    if (j2 < lim)
      acc += alf[j2][h] * (float)h1[(size_t)sedge[j2] * C1 + t];
    __syncthreads();
  }
  o1[(size_t)d * C1 + t] = (__bf16)fmaxf(acc + b1[t], 0.f);
}

// ---------------- layer-2 fused softmax+aggregate+bias+log_softmax ----------------
// wave per node, 4 nodes per block
__global__ __launch_bounds__(256) void gather2(const int* __restrict__ rowstart,
    const int* __restrict__ csr_src, const float* __restrict__ h2,
    const float* __restrict__ as2, const float* __restrict__ ad2,
    const float* __restrict__ b2, float* __restrict__ out, int N) {
  const int t = threadIdx.x;
  const int d = blockIdx.x * 4 + (t >> 6);
  const int c = t & 63;
  if (d >= N) return;
  const int r0 = rowstart[d];
  const int deg = rowstart[d + 1] - r0;
  const float add_d = ad2[d];
  const float self_sc = leaky(as2[d] + add_d);

  float mx = self_sc;
  for (int j = c; j < deg; j += 64)
    mx = fmaxf(mx, leaky(as2[csr_src[r0 + j]] + add_d));
#pragma unroll
  for (int o = 1; o < 64; o <<= 1) mx = fmaxf(mx, __shfl_xor(mx, o));

  float sum = 0.f;
  for (int j = c; j < deg; j += 64)
    sum += __expf(leaky(as2[csr_src[r0 + j]] + add_d) - mx);
#pragma unroll
  for (int o = 1; o < 64; o <<= 1) sum += __shfl_xor(sum, o);
  float es = __expf(self_sc - mx);
  sum += es;
  const float inv = 1.f / (sum + EPS);

  // shfl-broadcast alphas, 64-edge chunks
  float acc = es * inv * h2[(size_t)d * CLS + c];
  for (int c0 = 0; c0 < deg; c0 += 64) {
    const int jj = c0 + c;
    int s_c = 0; float al_c = 0.f;
    if (jj < deg) {
      s_c = csr_src[r0 + jj];
      al_c = __expf(leaky(as2[s_c] + add_d) - mx) * inv;
    }
    const int lim = min(64, deg - c0);
    for (int j2 = 0; j2 < lim; j2++) {
      int sj = __shfl(s_c, j2);
      float aj = __shfl(al_c, j2);
      acc += aj * h2[(size_t)sj * CLS + c];
    }
  }

  float v = acc + b2[c];
  float m2 = v;
#pragma unroll
  for (int o = 1; o < 64; o <<= 1) m2 = fmaxf(m2, __shfl_xor(m2, o));
  float ex = __expf(v - m2);
  float sm = ex;
#pragma unroll
  for (int o = 1; o < 64; o <<= 1) sm += __shfl_xor(sm, o);
  out[(size_t)d * CLS + c] = v - m2 - __logf(sm);
}

extern "C" void kernel_launch(void* const* d_in, const int* in_sizes, int n_in,
                              void* d_out, int out_size, void* d_ws, size_t ws_size,
                              hipStream_t stream) {
  const float* x        = (const float*)d_in[0];
  const int*   ei       = (const int*)d_in[1];
  const float* W1       = (const float*)d_in[2];
  const float* att_src1 = (const float*)d_in[3];
  const float* att_dst1 = (const float*)d_in[4];
  const float* b1       = (const float*)d_in[5];
  const float* W2       = (const float*)d_in[6];
  const float* att_src2 = (const float*)d_in[7];
  const float* att_dst2 = (const float*)d_in[8];
  const float* b2       = (const float*)d_in[9];
  float* out = (float*)d_out;

  const int N  = in_sizes[0] / F_IN;   // 50000
  const int E  = in_sizes[1] / 2;      // 800000

  char* ws = (char*)d_ws;
  size_t off = 0;
  auto alloc = [&](size_t bytes) -> void* {
    void* p = ws + off;
    off += (bytes + 255) & ~(size_t)255;
    return p;
  };
  __bf16* h1  = (__bf16*)alloc((size_t)N * C1 * 2);
  __bf16* o1  = (__bf16*)alloc((size_t)N * C1 * 2);
  float*  as1 = (float*)alloc((size_t)N * HEADS * 4);
  float*  ad1 = (float*)alloc((size_t)N * HEADS * 4);
  float*  h2  = (float*)alloc((size_t)N * CLS * 4);
  float*  as2 = (float*)alloc((size_t)N * 4);
  float*  ad2 = (float*)alloc((size_t)N * 4);
  int* deg      = (int*)alloc((size_t)N * 4);
  int* rowstart = (int*)alloc((size_t)(N + 1) * 4);
  int* cur      = (int*)alloc((size_t)N * 4);
  int* csr_src  = (int*)alloc((size_t)E * 4);
  __bf16* xb  = (__bf16*)alloc((size_t)N * F_IN * 2);
  __bf16* w1t = (__bf16*)alloc((size_t)C1 * F_IN * 2);
  __bf16* w2t = (__bf16*)alloc((size_t)CLS * C1 * 2);

  // ---- bf16 conversions ----
  cvt_x<<<(N * F_IN / 8 + 255) / 256, 256, 0, stream>>>(x, xb, N * F_IN / 8);
  cvt_w1t<<<(C1 * F_IN / 8 + 255) / 256, 256, 0, stream>>>(W1, w1t);
  cvt_w2t<<<(CLS * C1 / 8 + 255) / 256, 256, 0, stream>>>(W2, w2t);

  // ---- CSR build (self-loops implicit in gather kernels) ----
  hipMemsetAsync(deg, 0, (size_t)N * 4, stream);
  count_deg<<<(E + 255) / 256, 256, 0, stream>>>(ei, deg, E);
  scan_rows<<<1, 1024, 0, stream>>>(deg, rowstart, N);
  hipMemcpyAsync(cur, rowstart, (size_t)N * 4, hipMemcpyDeviceToDevice, stream);
  scatter_csr<<<(E + 255) / 256, 256, 0, stream>>>(ei, cur, csr_src, E);

  // ---- layer 1 ----
  {
    dim3 g(C1 / 128, (N + 127) / 128);
    gemm1_mfma<<<g, 256, 0, stream>>>(xb, w1t, h1, N);
  }
  att_scores1<<<N, 256, 0, stream>>>(h1, att_src1, att_dst1, as1, ad1);
  gather1<<<N, 256, 0, stream>>>(rowstart, csr_src, h1, as1, ad1, b1, o1);

  // ---- layer 2 ----
  gemm2_mfma<<<(N + 127) / 128, 256, 0, stream>>>(o1, w2t, h2, N);
  att_scores2<<<N, 64, 0, stream>>>(h2, att_src2, att_dst2, as2, ad2);
  gather2<<<(N + 3) / 4, 256, 0, stream>>>(rowstart, csr_src, h2, as2, ad2, b2, out, N);
}

// Round 5
// 564.837 us; speedup vs baseline: 4.0248x; 1.1367x over previous
//
#include <hip/hip_runtime.h>
#include <hip/hip_bf16.h>
#include <stdint.h>

#define F_IN 512
#define HID 32
#define HEADS 8
#define C1 (HEADS*HID)   // 256
#define CLS 64
#define NEG 0.2f
#define EPS 1e-16f

typedef __bf16 bf16x8 __attribute__((ext_vector_type(8)));
typedef __bf16 bf16x4 __attribute__((ext_vector_type(4)));
typedef float  f32x4  __attribute__((ext_vector_type(4)));

__device__ __forceinline__ float leaky(float v) { return v > 0.f ? v : NEG * v; }

// ---------------- fp32 -> bf16 conversions ----------------
__global__ __launch_bounds__(256) void cvt_x(const float* __restrict__ x,
    __bf16* __restrict__ xb, int total8) {
  int i = blockIdx.x * 256 + threadIdx.x;
  if (i >= total8) return;
  const float4* p = (const float4*)(x + (size_t)i * 8);
  float4 a = p[0], b = p[1];
  bf16x8 o;
  o[0] = (__bf16)a.x; o[1] = (__bf16)a.y; o[2] = (__bf16)a.z; o[3] = (__bf16)a.w;
  o[4] = (__bf16)b.x; o[5] = (__bf16)b.y; o[6] = (__bf16)b.z; o[7] = (__bf16)b.w;
  *(bf16x8*)(xb + (size_t)i * 8) = o;
}

__global__ __launch_bounds__(256) void cvt_w1t(const float* __restrict__ W1,
    __bf16* __restrict__ w1t) {
  int i = blockIdx.x * 256 + threadIdx.x;
  int o0 = i * 8;
  int c = o0 >> 9, k0 = o0 & 511;
  bf16x8 o;
#pragma unroll
  for (int j = 0; j < 8; j++) o[j] = (__bf16)W1[(size_t)(k0 + j) * C1 + c];
  *(bf16x8*)(w1t + (size_t)o0) = o;
}

__global__ __launch_bounds__(256) void cvt_w2t(const float* __restrict__ W2,
    __bf16* __restrict__ w2t) {
  int i = blockIdx.x * 256 + threadIdx.x;
  if (i >= CLS * C1 / 8) return;
  int o0 = i * 8;
  int c = o0 >> 8, k0 = o0 & 255;
  bf16x8 o;
#pragma unroll
  for (int j = 0; j < 8; j++) o[j] = (__bf16)W2[(size_t)(k0 + j) * CLS + c];
  *(bf16x8*)(w2t + (size_t)o0) = o;
}

// ---------------- MFMA GEMM1: h1[M,256] = xb[M,512] @ w1t^T, out bf16 ----------------
__global__ __launch_bounds__(256) void gemm1_mfma(const __bf16* __restrict__ A,
    const __bf16* __restrict__ Bt, __bf16* __restrict__ C, int M) {
  __shared__ __bf16 Al[128 * 32];
  __shared__ __bf16 Bl[128 * 32];
  const int tid  = threadIdx.x;
  const int lane = tid & 63;
  const int wave = tid >> 6;
  const int lm = lane & 15, q = lane >> 4;
  const int wr = (wave >> 1) * 64, wc = (wave & 1) * 64;
  const int bm = blockIdx.y * 128, bn = blockIdx.x * 128;

  const int srow = tid >> 2;
  const int skc  = (tid & 3) * 8;

  f32x4 acc[4][4];
#pragma unroll
  for (int i = 0; i < 4; i++)
#pragma unroll
    for (int j = 0; j < 4; j++) acc[i][j] = (f32x4){0.f, 0.f, 0.f, 0.f};

  const int ra0 = min(bm + srow, M - 1);
  const int ra1 = min(bm + srow + 64, M - 1);
  const int rb0 = bn + srow, rb1 = bn + srow + 64;

  bf16x8 va0, va1, vb0, vb1;
  va0 = *(const bf16x8*)(A + (size_t)ra0 * 512 + skc);
  va1 = *(const bf16x8*)(A + (size_t)ra1 * 512 + skc);
  vb0 = *(const bf16x8*)(Bt + (size_t)rb0 * 512 + skc);
  vb1 = *(const bf16x8*)(Bt + (size_t)rb1 * 512 + skc);

  for (int kk = 0; kk < 16; kk++) {
    __syncthreads();
    *(bf16x8*)(Al + srow * 32 + skc)        = va0;
    *(bf16x8*)(Al + (srow + 64) * 32 + skc) = va1;
    *(bf16x8*)(Bl + srow * 32 + skc)        = vb0;
    *(bf16x8*)(Bl + (srow + 64) * 32 + skc) = vb1;
    __syncthreads();
    if (kk + 1 < 16) {
      const int k0 = (kk + 1) * 32;
      va0 = *(const bf16x8*)(A + (size_t)ra0 * 512 + k0 + skc);
      va1 = *(const bf16x8*)(A + (size_t)ra1 * 512 + k0 + skc);
      vb0 = *(const bf16x8*)(Bt + (size_t)rb0 * 512 + k0 + skc);
      vb1 = *(const bf16x8*)(Bt + (size_t)rb1 * 512 + k0 + skc);
    }
    bf16x8 af[4], bfr[4];
#pragma unroll
    for (int mi = 0; mi < 4; mi++)
      af[mi] = *(const bf16x8*)(Al + (wr + mi * 16 + lm) * 32 + q * 8);
#pragma unroll
    for (int ni = 0; ni < 4; ni++)
      bfr[ni] = *(const bf16x8*)(Bl + (wc + ni * 16 + lm) * 32 + q * 8);
#pragma unroll
    for (int mi = 0; mi < 4; mi++)
#pragma unroll
      for (int ni = 0; ni < 4; ni++)
        acc[mi][ni] = __builtin_amdgcn_mfma_f32_16x16x32_bf16(af[mi], bfr[ni], acc[mi][ni], 0, 0, 0);
  }

#pragma unroll
  for (int mi = 0; mi < 4; mi++) {
#pragma unroll
    for (int ni = 0; ni < 4; ni++) {
      const int col = bn + wc + ni * 16 + lm;
#pragma unroll
      for (int r = 0; r < 4; r++) {
        const int row = bm + wr + mi * 16 + q * 4 + r;
        if (row < M) C[(size_t)row * C1 + col] = (__bf16)acc[mi][ni][r];
      }
    }
  }
}

// ---------------- MFMA GEMM2: h2[M,64] = o1[M,256] @ w2t^T, out fp32 ----------------
__global__ __launch_bounds__(256) void gemm2_mfma(const __bf16* __restrict__ A,
    const __bf16* __restrict__ Bt, float* __restrict__ C, int M) {
  __shared__ __bf16 Al[128 * 32];
  __shared__ __bf16 Bl[64 * 32];
  const int tid  = threadIdx.x;
  const int lane = tid & 63;
  const int wave = tid >> 6;
  const int lm = lane & 15, q = lane >> 4;
  const int wr = (wave >> 1) * 64, wc = (wave & 1) * 32;
  const int bm = blockIdx.x * 128;

  const int srow = tid >> 2;
  const int skc  = (tid & 3) * 8;

  f32x4 acc[4][2];
#pragma unroll
  for (int i = 0; i < 4; i++)
#pragma unroll
    for (int j = 0; j < 2; j++) acc[i][j] = (f32x4){0.f, 0.f, 0.f, 0.f};

  const int ra0 = min(bm + srow, M - 1);
  const int ra1 = min(bm + srow + 64, M - 1);

  bf16x8 va0, va1, vb;
  va0 = *(const bf16x8*)(A + (size_t)ra0 * C1 + skc);
  va1 = *(const bf16x8*)(A + (size_t)ra1 * C1 + skc);
  vb  = *(const bf16x8*)(Bt + (size_t)srow * C1 + skc);

  for (int kk = 0; kk < 8; kk++) {
    __syncthreads();
    *(bf16x8*)(Al + srow * 32 + skc)        = va0;
    *(bf16x8*)(Al + (srow + 64) * 32 + skc) = va1;
    *(bf16x8*)(Bl + srow * 32 + skc)        = vb;
    __syncthreads();
    if (kk + 1 < 8) {
      const int k0 = (kk + 1) * 32;
      va0 = *(const bf16x8*)(A + (size_t)ra0 * C1 + k0 + skc);
      va1 = *(const bf16x8*)(A + (size_t)ra1 * C1 + k0 + skc);
      vb  = *(const bf16x8*)(Bt + (size_t)srow * C1 + k0 + skc);
    }
    bf16x8 af[4], bfr[2];
#pragma unroll
    for (int mi = 0; mi < 4; mi++)
      af[mi] = *(const bf16x8*)(Al + (wr + mi * 16 + lm) * 32 + q * 8);
#pragma unroll
    for (int ni = 0; ni < 2; ni++)
      bfr[ni] = *(const bf16x8*)(Bl + (wc + ni * 16 + lm) * 32 + q * 8);
#pragma unroll
    for (int mi = 0; mi < 4; mi++)
#pragma unroll
      for (int ni = 0; ni < 2; ni++)
        acc[mi][ni] = __builtin_amdgcn_mfma_f32_16x16x32_bf16(af[mi], bfr[ni], acc[mi][ni], 0, 0, 0);
  }

#pragma unroll
  for (int mi = 0; mi < 4; mi++) {
#pragma unroll
    for (int ni = 0; ni < 2; ni++) {
      const int col = wc + ni * 16 + lm;
#pragma unroll
      for (int r = 0; r < 4; r++) {
        const int row = bm + wr + mi * 16 + q * 4 + r;
        if (row < M) C[(size_t)row * CLS + col] = acc[mi][ni][r];
      }
    }
  }
}

// ---------------- attention score dots ----------------
__global__ __launch_bounds__(256) void att_scores1(const __bf16* __restrict__ h1,
    const float* __restrict__ asw, const float* __restrict__ adw,
    float* __restrict__ a_src, float* __restrict__ a_dst) {
  int n = blockIdx.x, t = threadIdx.x;
  float v  = (float)h1[(size_t)n * C1 + t];
  float ps = v * asw[t];
  float pd = v * adw[t];
#pragma unroll
  for (int o = 16; o >= 1; o >>= 1) {
    ps += __shfl_xor(ps, o);
    pd += __shfl_xor(pd, o);
  }
  if ((t & 31) == 0) {
    a_src[n * HEADS + (t >> 5)] = ps;
    a_dst[n * HEADS + (t >> 5)] = pd;
  }
}

__global__ __launch_bounds__(64) void att_scores2(const float* __restrict__ h2,
    const float* __restrict__ asw, const float* __restrict__ adw,
    float* __restrict__ a_src, float* __restrict__ a_dst) {
  int n = blockIdx.x, c = threadIdx.x;
  float v  = h2[(size_t)n * CLS + c];
  float ps = v * asw[c];
  float pd = v * adw[c];
#pragma unroll
  for (int o = 32; o >= 1; o >>= 1) {
    ps += __shfl_xor(ps, o);
    pd += __shfl_xor(pd, o);
  }
  if (c == 0) { a_src[n] = ps; a_dst[n] = pd; }
}

// ---------------- CSR build (dst-indexed; self-loops implicit) ----------------
__global__ __launch_bounds__(256) void count_deg(const int* __restrict__ ei,
    int* __restrict__ deg, int E) {
  int e = blockIdx.x * 256 + threadIdx.x;
  if (e < E) atomicAdd(&deg[ei[E + e]], 1);
}

__global__ __launch_bounds__(1024) void scan_rows(const int* __restrict__ deg,
    int* __restrict__ rowstart, int N) {
  __shared__ int wpart[16];
  __shared__ int s_carry;
  const int t = threadIdx.x, lane = t & 63, wid = t >> 6;
  if (t == 0) s_carry = 0;
  __syncthreads();
  for (int base = 0; base < N; base += 8192) {
    int i0 = base + t * 8;
    int d0[8], s8 = 0;
#pragma unroll
    for (int k = 0; k < 8; k++) { int i = i0 + k; d0[k] = (i < N) ? deg[i] : 0; s8 += d0[k]; }
    int v = s8;
#pragma unroll
    for (int off = 1; off < 64; off <<= 1) { int x = __shfl_up(v, off); if (lane >= off) v += x; }
    if (lane == 63) wpart[wid] = v;
    __syncthreads();
    if (wid == 0) {
      int w = (lane < 16) ? wpart[lane] : 0;
#pragma unroll
      for (int off = 1; off < 16; off <<= 1) { int x = __shfl_up(w, off); if (lane >= off) w += x; }
      if (lane < 16) wpart[lane] = w;
    }
    __syncthreads();
    int excl = s_carry + (wid > 0 ? wpart[wid - 1] : 0) + v - s8;
#pragma unroll
    for (int k = 0; k < 8; k++) { int i = i0 + k; if (i < N) rowstart[i] = excl; excl += d0[k]; }
    __syncthreads();
    if (t == 0) s_carry += wpart[15];
    __syncthreads();
  }
  if (t == 0) rowstart[N] = s_carry;
}

__global__ __launch_bounds__(256) void scatter_csr(const int* __restrict__ ei,
    int* __restrict__ cur, int* __restrict__ csr_src, int E) {
  int e = blockIdx.x * 256 + threadIdx.x;
  if (e >= E) return;
  int s = ei[e], d = ei[E + e];
  int pos = atomicAdd(&cur[d], 1);
  csr_src[pos] = s;
}

// ---------------- layer-1 fused softmax+aggregate+bias+relu ----------------
// ONE WAVE per dest node, 4 nodes/block. No LDS, no barriers.
// Score lanes: (e8 = lane>>3, hh = lane&7). Agg: lane covers channels 4l..4l+3 (head h3 = lane>>3).
__global__ __launch_bounds__(256) void gather1(const int* __restrict__ rowstart,
    const int* __restrict__ csr_src, const __bf16* __restrict__ h1,
    const float* __restrict__ as1, const float* __restrict__ ad1,
    const float* __restrict__ b1, __bf16* __restrict__ o1, int N) {
  const int t = threadIdx.x;
  const int d = blockIdx.x * 4 + (t >> 6);
  if (d >= N) return;
  const int lane = t & 63;
  const int e8 = lane >> 3, hh = lane & 7;
  const int h3 = lane >> 3;           // head for aggregation channels
  const int r0 = rowstart[d];
  const int deg = rowstart[d + 1] - r0;

  const float addh = ad1[(size_t)d * 8 + hh];
  const float self_sc = leaky(as1[(size_t)d * 8 + hh] + addh);

  // --- cached scores for first 64 edges (registers, unrolled+predicated) ---
  int   se[8];
  float sc[8];
#pragma unroll
  for (int ch = 0; ch < 8; ch++) {
    const int j = ch * 8 + e8;
    se[ch] = 0; sc[ch] = -3.4e38f;
    if (j < deg) {
      int s = csr_src[r0 + j];
      se[ch] = s;
      sc[ch] = leaky(as1[(size_t)s * 8 + hh] + addh);
    }
  }
  // max
  float mx = -3.4e38f;
#pragma unroll
  for (int ch = 0; ch < 8; ch++) mx = fmaxf(mx, sc[ch]);
  for (int j0 = 64; j0 < deg; j0 += 8) {     // rare tail
    int j = j0 + e8;
    if (j < deg) {
      int s = csr_src[r0 + j];
      mx = fmaxf(mx, leaky(as1[(size_t)s * 8 + hh] + addh));
    }
  }
  mx = fmaxf(mx, __shfl_xor(mx, 8));
  mx = fmaxf(mx, __shfl_xor(mx, 16));
  mx = fmaxf(mx, __shfl_xor(mx, 32));
  mx = fmaxf(mx, self_sc);

  // sum of exp
  float sum = 0.f;
#pragma unroll
  for (int ch = 0; ch < 8; ch++)
    if (ch * 8 + e8 < deg) sum += __expf(sc[ch] - mx);
  for (int j0 = 64; j0 < deg; j0 += 8) {
    int j = j0 + e8;
    if (j < deg) {
      int s = csr_src[r0 + j];
      sum += __expf(leaky(as1[(size_t)s * 8 + hh] + addh) - mx);
    }
  }
  sum += __shfl_xor(sum, 8);
  sum += __shfl_xor(sum, 16);
  sum += __shfl_xor(sum, 32);
  sum += __expf(self_sc - mx);
  const float inv = 1.f / (sum + EPS);

  // alphas for cached edges (per score-lane), self alpha
  float al[8];
#pragma unroll
  for (int ch = 0; ch < 8; ch++) al[ch] = __expf(sc[ch] - mx) * inv;
  const float al_self_byhh = __expf(self_sc - mx) * inv;

  // --- aggregation: 4 channels per lane (8B bf16x4 loads) ---
  const float a_self = __shfl(al_self_byhh, h3);   // head value for this lane's channels
  f32x4 acc;
  {
    bf16x4 x = *(const bf16x4*)(h1 + (size_t)d * C1 + lane * 4);
    acc[0] = a_self * (float)x[0]; acc[1] = a_self * (float)x[1];
    acc[2] = a_self * (float)x[2]; acc[3] = a_self * (float)x[3];
  }
#pragma unroll
  for (int ch = 0; ch < 8; ch++) {
#pragma unroll
    for (int jj = 0; jj < 8; jj++) {
      const int j = ch * 8 + jj;
      if (j < deg) {                       // wave-uniform -> cheap branch
        const int   s_j = __shfl(se[ch], jj * 8);
        const float a_j = __shfl(al[ch], jj * 8 + h3);
        bf16x4 x = *(const bf16x4*)(h1 + (size_t)s_j * C1 + lane * 4);
        acc[0] += a_j * (float)x[0]; acc[1] += a_j * (float)x[1];
        acc[2] += a_j * (float)x[2]; acc[3] += a_j * (float)x[3];
      }
    }
  }
  // rare tail (deg > 64)
  for (int j0 = 64; j0 < deg; j0 += 8) {
    int j = j0 + e8;
    int s = 0; float alt = 0.f;
    if (j < deg) {
      s = csr_src[r0 + j];
      alt = __expf(leaky(as1[(size_t)s * 8 + hh] + addh) - mx) * inv;
    }
    for (int jj = 0; jj < 8; jj++) {
      if (j0 + jj < deg) {
        const int   s_j = __shfl(s, jj * 8);
        const float a_j = __shfl(alt, jj * 8 + h3);
        bf16x4 x = *(const bf16x4*)(h1 + (size_t)s_j * C1 + lane * 4);
        acc[0] += a_j * (float)x[0]; acc[1] += a_j * (float)x[1];
        acc[2] += a_j * (float)x[2]; acc[3] += a_j * (float)x[3];
      }
    }
  }

  // bias + relu, write bf16x4
  const float4 b4 = *(const float4*)(b1 + lane * 4);
  bf16x4 o;
  o[0] = (__bf16)fmaxf(acc[0] + b4.x, 0.f);
  o[1] = (__bf16)fmaxf(acc[1] + b4.y, 0.f);
  o[2] = (__bf16)fmaxf(acc[2] + b4.z, 0.f);
  o[3] = (__bf16)fmaxf(acc[3] + b4.w, 0.f);
  *(bf16x4*)(o1 + (size_t)d * C1 + lane * 4) = o;
}

// ---------------- layer-2 fused softmax+aggregate+bias+log_softmax ----------------
__global__ __launch_bounds__(256) void gather2(const int* __restrict__ rowstart,
    const int* __restrict__ csr_src, const float* __restrict__ h2,
    const float* __restrict__ as2, const float* __restrict__ ad2,
    const float* __restrict__ b2, float* __restrict__ out, int N) {
  const int t = threadIdx.x;
  const int d = blockIdx.x * 4 + (t >> 6);
  const int c = t & 63;
  if (d >= N) return;
  const int r0 = rowstart[d];
  const int deg = rowstart[d + 1] - r0;
  const float add_d = ad2[d];
  const float self_sc = leaky(as2[d] + add_d);

  float mx = self_sc;
  for (int j = c; j < deg; j += 64)
    mx = fmaxf(mx, leaky(as2[csr_src[r0 + j]] + add_d));
#pragma unroll
  for (int o = 1; o < 64; o <<= 1) mx = fmaxf(mx, __shfl_xor(mx, o));

  float sum = 0.f;
  for (int j = c; j < deg; j += 64)
    sum += __expf(leaky(as2[csr_src[r0 + j]] + add_d) - mx);
#pragma unroll
  for (int o = 1; o < 64; o <<= 1) sum += __shfl_xor(sum, o);
  float es = __expf(self_sc - mx);
  sum += es;
  const float inv = 1.f / (sum + EPS);

  float acc = es * inv * h2[(size_t)d * CLS + c];
  for (int c0 = 0; c0 < deg; c0 += 64) {
    const int jj = c0 + c;
    int s_c = 0; float al_c = 0.f;
    if (jj < deg) {
      s_c = csr_src[r0 + jj];
      al_c = __expf(leaky(as2[s_c] + add_d) - mx) * inv;
    }
    const int lim = min(64, deg - c0);
    for (int j2 = 0; j2 < lim; j2++) {
      int sj = __shfl(s_c, j2);
      float aj = __shfl(al_c, j2);
      acc += aj * h2[(size_t)sj * CLS + c];
    }
  }

  float v = acc + b2[c];
  float m2 = v;
#pragma unroll
  for (int o = 1; o < 64; o <<= 1) m2 = fmaxf(m2, __shfl_xor(m2, o));
  float ex = __expf(v - m2);
  float sm = ex;
#pragma unroll
  for (int o = 1; o < 64; o <<= 1) sm += __shfl_xor(sm, o);
  out[(size_t)d * CLS + c] = v - m2 - __logf(sm);
}

extern "C" void kernel_launch(void* const* d_in, const int* in_sizes, int n_in,
                              void* d_out, int out_size, void* d_ws, size_t ws_size,
                              hipStream_t stream) {
  const float* x        = (const float*)d_in[0];
  const int*   ei       = (const int*)d_in[1];
  const float* W1       = (const float*)d_in[2];
  const float* att_src1 = (const float*)d_in[3];
  const float* att_dst1 = (const float*)d_in[4];
  const float* b1       = (const float*)d_in[5];
  const float* W2       = (const float*)d_in[6];
  const float* att_src2 = (const float*)d_in[7];
  const float* att_dst2 = (const float*)d_in[8];
  const float* b2       = (const float*)d_in[9];
  float* out = (float*)d_out;

  const int N  = in_sizes[0] / F_IN;   // 50000
  const int E  = in_sizes[1] / 2;      // 800000

  char* ws = (char*)d_ws;
  size_t off = 0;
  auto alloc = [&](size_t bytes) -> void* {
    void* p = ws + off;
    off += (bytes + 255) & ~(size_t)255;
    return p;
  };
  __bf16* h1  = (__bf16*)alloc((size_t)N * C1 * 2);
  __bf16* o1  = (__bf16*)alloc((size_t)N * C1 * 2);
  float*  as1 = (float*)alloc((size_t)N * HEADS * 4);
  float*  ad1 = (float*)alloc((size_t)N * HEADS * 4);
  float*  h2  = (float*)alloc((size_t)N * CLS * 4);
  float*  as2 = (float*)alloc((size_t)N * 4);
  float*  ad2 = (float*)alloc((size_t)N * 4);
  int* deg      = (int*)alloc((size_t)N * 4);
  int* rowstart = (int*)alloc((size_t)(N + 1) * 4);
  int* cur      = (int*)alloc((size_t)N * 4);
  int* csr_src  = (int*)alloc((size_t)E * 4);
  __bf16* xb  = (__bf16*)alloc((size_t)N * F_IN * 2);
  __bf16* w1t = (__bf16*)alloc((size_t)C1 * F_IN * 2);
  __bf16* w2t = (__bf16*)alloc((size_t)CLS * C1 * 2);

  // ---- bf16 conversions ----
  cvt_x<<<(N * F_IN / 8 + 255) / 256, 256, 0, stream>>>(x, xb, N * F_IN / 8);
  cvt_w1t<<<(C1 * F_IN / 8 + 255) / 256, 256, 0, stream>>>(W1, w1t);
  cvt_w2t<<<(CLS * C1 / 8 + 255) / 256, 256, 0, stream>>>(W2, w2t);

  // ---- CSR build (self-loops implicit in gather kernels) ----
  hipMemsetAsync(deg, 0, (size_t)N * 4, stream);
  count_deg<<<(E + 255) / 256, 256, 0, stream>>>(ei, deg, E);
  scan_rows<<<1, 1024, 0, stream>>>(deg, rowstart, N);
  hipMemcpyAsync(cur, rowstart, (size_t)N * 4, hipMemcpyDeviceToDevice, stream);
  scatter_csr<<<(E + 255) / 256, 256, 0, stream>>>(ei, cur, csr_src, E);

  // ---- layer 1 ----
  {
    dim3 g(C1 / 128, (N + 127) / 128);
    gemm1_mfma<<<g, 256, 0, stream>>>(xb, w1t, h1, N);
  }
  att_scores1<<<N, 256, 0, stream>>>(h1, att_src1, att_dst1, as1, ad1);
  gather1<<<(N + 3) / 4, 256, 0, stream>>>(rowstart, csr_src, h1, as1, ad1, b1, o1, N);

  // ---- layer 2 ----
  gemm2_mfma<<<(N + 127) / 128, 256, 0, stream>>>(o1, w2t, h2, N);
  att_scores2<<<N, 64, 0, stream>>>(h2, att_src2, att_dst2, as2, ad2);
  gather2<<<(N + 3) / 4, 256, 0, stream>>>(rowstart, csr_src, h2, as2, ad2, b2, out, N);
}